// Round 6
// baseline (125.593 us; speedup 1.0000x reference)
//
#include <hip/hip_runtime.h>

// SpatialTransformer bilinear sampling, B=16 H=512 W=512 C=16 fp32.
// Round 6: R2 structure (NT stores CONFIRMED +23us by R5 A/B) but pixel
// pairs are HORIZONTAL (xw, xw+1 same row) instead of vertical:
//  - one NT v4f def load replaces two v2f loads (12 -> 11 VMEM inst/thread)
//  - adjacent-x gather windows share source lines (x1(p) == x0(p+1) often)
//  - store instructions still write full 64B lines (4 lanes x 16B / pixel)

#define H_ 512
#define W_ 512

typedef float v2f __attribute__((ext_vector_type(2)));
typedef float v4f __attribute__((ext_vector_type(4)));

__device__ __forceinline__ v4f bilerp_quad(const float* __restrict__ base,
                                           int cq, int xw, int y, float dxf, float dyf)
{
    // coords in padded frame (pad=1), exactly per reference
    float xf = dxf + (float)xw + 1.0f;
    float yf = dyf + (float)y  + 1.0f;

    int x0 = (int)floorf(xf);
    int y0 = (int)floorf(yf);
    int x1 = min(max(x0 + 1, 0), W_ + 1);
    int y1 = min(max(y0 + 1, 0), H_ + 1);
    x0 = min(max(x0, 0), W_ + 1);
    y0 = min(max(y0, 0), H_ + 1);

    float dx = (float)x1 - xf;
    float dy = (float)y1 - yf;

    // padded index i maps to real pixel i-1 iff 1 <= i <= 512, else zero pad
    float vx0 = (x0 >= 1 && x0 <= W_) ? 1.0f : 0.0f;
    float vx1 = (x1 >= 1 && x1 <= W_) ? 1.0f : 0.0f;
    float vy0 = (y0 >= 1 && y0 <= H_) ? 1.0f : 0.0f;
    float vy1 = (y1 >= 1 && y1 <= H_) ? 1.0f : 0.0f;

    int xc0 = min(max(x0, 1), W_) - 1;
    int xc1 = min(max(x1, 1), W_) - 1;
    int yc0 = min(max(y0, 1), H_) - 1;
    int yc1 = min(max(y1, 1), H_) - 1;

    const float* pa = base + ((size_t)((yc0 << 9) | xc0) << 4) + cq;
    const float* pb = base + ((size_t)((yc1 << 9) | xc0) << 4) + cq;
    const float* pc = base + ((size_t)((yc0 << 9) | xc1) << 4) + cq;
    const float* pd = base + ((size_t)((yc1 << 9) | xc1) << 4) + cq;

    v4f Ia = *reinterpret_cast<const v4f*>(pa);
    v4f Ib = *reinterpret_cast<const v4f*>(pb);
    v4f Ic = *reinterpret_cast<const v4f*>(pc);
    v4f Id = *reinterpret_cast<const v4f*>(pd);

    float wa = dx * dy                   * (vx0 * vy0);
    float wb = dx * (1.0f - dy)          * (vx0 * vy1);
    float wc = (1.0f - dx) * dy          * (vx1 * vy0);
    float wd = (1.0f - dx) * (1.0f - dy) * (vx1 * vy1);

    return wa * Ia + wb * Ib + wc * Ic + wd * Id;
}

__global__ __launch_bounds__(256) void st_bilinear2h(
    const float* __restrict__ img,   // [B,H,W,C]
    const float* __restrict__ def,   // [B,H,W,2]
    float* __restrict__ out)         // [B,H,W,C]
{
    int tid = blockIdx.x * 256 + threadIdx.x;   // [0, 8388608)
    int cq  = (tid & 3) << 2;                   // channel offset 0,4,8,12
    int pp  = tid >> 2;                         // pixel-pair index (x-pairs)
    int xp  = (pp & 255) << 1;                  // even column
    int y   = (pp >> 8) & 511;
    int b   = pp >> 17;
    int p0  = (b << 18) | (y << 9) | xp;        // pixel (y, xp)
    int p1  = p0 + 1;                           // pixel (y, xp+1)

    const float* base = img + ((size_t)b << 22);

    // one 16B NT load covers both pixels' deformations
    v4f d = __builtin_nontemporal_load(
        reinterpret_cast<const v4f*>(def + ((size_t)p0 << 1)));

    v4f r0 = bilerp_quad(base, cq, xp,     y, d.x, d.y);
    v4f r1 = bilerp_quad(base, cq, xp + 1, y, d.z, d.w);

    float* op = out + ((size_t)p0 << 4) + cq;
    __builtin_nontemporal_store(r0, reinterpret_cast<v4f*>(op));
    __builtin_nontemporal_store(r1, reinterpret_cast<v4f*>(op + 16));
}

extern "C" void kernel_launch(void* const* d_in, const int* in_sizes, int n_in,
                              void* d_out, int out_size, void* d_ws, size_t ws_size,
                              hipStream_t stream) {
    const float* img = (const float*)d_in[0];   // moving_image [B,H,W,C]
    const float* def = (const float*)d_in[1];   // deformation  [B,H,W,2]
    float* out = (float*)d_out;

    const int total_threads = 16 * 512 * 512 * 4 / 2;  // 2 pixels per thread
    const int block = 256;
    const int grid = total_threads / block;            // 32768

    st_bilinear2h<<<grid, block, 0, stream>>>(img, def, out);
}

// Round 7
// 97.491 us; speedup vs baseline: 1.2883x; 1.2883x over previous
//
#include <hip/hip_runtime.h>

// SpatialTransformer bilinear sampling, B=16 H=512 W=512 C=16 fp32.
// Round 7: EXACT R2 body (champion, 94.7us: 2 row-adjacent px/thread,
// branchless clamp+mask gathers, NT def loads, NT out stores) + ONE lever:
// bijective XCD-chunked block swizzle (32768 blocks % 8 == 0), so each
// XCD's concurrent blocks are CONSECUTIVE -> contiguous ~16-row gather
// window resident in that XCD's 4MB L2, 8 XCDs hold distinct regions.

#define H_ 512
#define W_ 512

typedef float v2f __attribute__((ext_vector_type(2)));
typedef float v4f __attribute__((ext_vector_type(4)));

__device__ __forceinline__ v4f bilerp_quad(const float* __restrict__ base,
                                           int cq, int xw, int y, v2f d)
{
    // coords in padded frame (pad=1), exactly per reference
    float xf = d.x + (float)xw + 1.0f;
    float yf = d.y + (float)y  + 1.0f;

    int x0 = (int)floorf(xf);
    int y0 = (int)floorf(yf);
    int x1 = min(max(x0 + 1, 0), W_ + 1);
    int y1 = min(max(y0 + 1, 0), H_ + 1);
    x0 = min(max(x0, 0), W_ + 1);
    y0 = min(max(y0, 0), H_ + 1);

    float dx = (float)x1 - xf;
    float dy = (float)y1 - yf;

    // padded index i maps to real pixel i-1 iff 1 <= i <= 512, else zero pad
    float vx0 = (x0 >= 1 && x0 <= W_) ? 1.0f : 0.0f;
    float vx1 = (x1 >= 1 && x1 <= W_) ? 1.0f : 0.0f;
    float vy0 = (y0 >= 1 && y0 <= H_) ? 1.0f : 0.0f;
    float vy1 = (y1 >= 1 && y1 <= H_) ? 1.0f : 0.0f;

    int xc0 = min(max(x0, 1), W_) - 1;
    int xc1 = min(max(x1, 1), W_) - 1;
    int yc0 = min(max(y0, 1), H_) - 1;
    int yc1 = min(max(y1, 1), H_) - 1;

    const float* pa = base + ((size_t)((yc0 << 9) | xc0) << 4) + cq;
    const float* pb = base + ((size_t)((yc1 << 9) | xc0) << 4) + cq;
    const float* pc = base + ((size_t)((yc0 << 9) | xc1) << 4) + cq;
    const float* pd = base + ((size_t)((yc1 << 9) | xc1) << 4) + cq;

    v4f Ia = *reinterpret_cast<const v4f*>(pa);
    v4f Ib = *reinterpret_cast<const v4f*>(pb);
    v4f Ic = *reinterpret_cast<const v4f*>(pc);
    v4f Id = *reinterpret_cast<const v4f*>(pd);

    float wa = dx * dy                   * (vx0 * vy0);
    float wb = dx * (1.0f - dy)          * (vx0 * vy1);
    float wc = (1.0f - dx) * dy          * (vx1 * vy0);
    float wd = (1.0f - dx) * (1.0f - dy) * (vx1 * vy1);

    return wa * Ia + wb * Ib + wc * Ic + wd * Id;
}

__global__ __launch_bounds__(256) void st_bilinear2_xcd(
    const float* __restrict__ img,   // [B,H,W,C]
    const float* __restrict__ def,   // [B,H,W,2]
    float* __restrict__ out)         // [B,H,W,C]
{
    // Bijective XCD-chunked swizzle: 32768 blocks = 8 chunks of 4096.
    // HW round-robins blockIdx over XCDs; XCD k gets contiguous chunk k.
    int sbid = (blockIdx.x & 7) * 4096 + (blockIdx.x >> 3);
    int tid  = sbid * 256 + threadIdx.x;        // [0, 8388608)

    int cq  = (tid & 3) << 2;                   // channel offset 0,4,8,12
    int pp  = tid >> 2;                         // pixel-pair index
    int xw  = pp & 511;
    int yh  = (pp >> 9) & 255;
    int b   = pp >> 17;
    int yr  = yh << 1;                          // even row
    int p0  = (b << 18) | (yr << 9) | xw;       // pixel index of row yr
    int p1  = p0 + W_;                          // pixel index of row yr+1

    const float* base = img + ((size_t)b << 22);

    v2f d0 = __builtin_nontemporal_load(
        reinterpret_cast<const v2f*>(def + ((size_t)p0 << 1)));
    v2f d1 = __builtin_nontemporal_load(
        reinterpret_cast<const v2f*>(def + ((size_t)p1 << 1)));

    v4f r0 = bilerp_quad(base, cq, xw, yr,     d0);
    v4f r1 = bilerp_quad(base, cq, xw, yr + 1, d1);

    __builtin_nontemporal_store(r0, reinterpret_cast<v4f*>(out + ((size_t)p0 << 4) + cq));
    __builtin_nontemporal_store(r1, reinterpret_cast<v4f*>(out + ((size_t)p1 << 4) + cq));
}

extern "C" void kernel_launch(void* const* d_in, const int* in_sizes, int n_in,
                              void* d_out, int out_size, void* d_ws, size_t ws_size,
                              hipStream_t stream) {
    const float* img = (const float*)d_in[0];   // moving_image [B,H,W,C]
    const float* def = (const float*)d_in[1];   // deformation  [B,H,W,2]
    float* out = (float*)d_out;

    const int total_threads = 16 * 512 * 512 * 4 / 2;  // 2 pixels per thread
    const int block = 256;
    const int grid = total_threads / block;            // 32768 (divisible by 8)

    st_bilinear2_xcd<<<grid, block, 0, stream>>>(img, def, out);
}

// Round 8
// 94.349 us; speedup vs baseline: 1.3312x; 1.0333x over previous
//
#include <hip/hip_runtime.h>

// SpatialTransformer bilinear sampling, B=16 H=512 W=512 C=16 fp32.
// FINAL (= R2 champion, 94.7us): 2 row-adjacent pixels per thread,
// branchless clamp+mask gathers, NT def loads, NT output stores.
// Isolated-lever ledger from this session:
//   - NT stores: +23us (R5 A/B) -- keeps 262MB output stream from evicting
//     the 268MB image out of the 256MB L3; store instrs MUST be full-density
//     (R6: half-density NT stores doubled FETCH via HBM read-modify-write).
//   - 2px vertical per thread: best decomposition (R3 4px: reg-starved
//     serialization; R6 horizontal: sparse stores).
//   - phase-split gather clustering: neutral (R4) -- compiler already does it.
//   - XCD-chunked swizzle: neutral (R7) -- FETCH unchanged, no L2 gain.

#define H_ 512
#define W_ 512

typedef float v2f __attribute__((ext_vector_type(2)));
typedef float v4f __attribute__((ext_vector_type(4)));

__device__ __forceinline__ v4f bilerp_quad(const float* __restrict__ base,
                                           int cq, int xw, int y, v2f d)
{
    // coords in padded frame (pad=1), exactly per reference
    float xf = d.x + (float)xw + 1.0f;
    float yf = d.y + (float)y  + 1.0f;

    int x0 = (int)floorf(xf);
    int y0 = (int)floorf(yf);
    int x1 = min(max(x0 + 1, 0), W_ + 1);
    int y1 = min(max(y0 + 1, 0), H_ + 1);
    x0 = min(max(x0, 0), W_ + 1);
    y0 = min(max(y0, 0), H_ + 1);

    float dx = (float)x1 - xf;
    float dy = (float)y1 - yf;

    // padded index i maps to real pixel i-1 iff 1 <= i <= 512, else zero pad
    float vx0 = (x0 >= 1 && x0 <= W_) ? 1.0f : 0.0f;
    float vx1 = (x1 >= 1 && x1 <= W_) ? 1.0f : 0.0f;
    float vy0 = (y0 >= 1 && y0 <= H_) ? 1.0f : 0.0f;
    float vy1 = (y1 >= 1 && y1 <= H_) ? 1.0f : 0.0f;

    int xc0 = min(max(x0, 1), W_) - 1;
    int xc1 = min(max(x1, 1), W_) - 1;
    int yc0 = min(max(y0, 1), H_) - 1;
    int yc1 = min(max(y1, 1), H_) - 1;

    const float* pa = base + ((size_t)((yc0 << 9) | xc0) << 4) + cq;
    const float* pb = base + ((size_t)((yc1 << 9) | xc0) << 4) + cq;
    const float* pc = base + ((size_t)((yc0 << 9) | xc1) << 4) + cq;
    const float* pd = base + ((size_t)((yc1 << 9) | xc1) << 4) + cq;

    v4f Ia = *reinterpret_cast<const v4f*>(pa);
    v4f Ib = *reinterpret_cast<const v4f*>(pb);
    v4f Ic = *reinterpret_cast<const v4f*>(pc);
    v4f Id = *reinterpret_cast<const v4f*>(pd);

    float wa = dx * dy                   * (vx0 * vy0);
    float wb = dx * (1.0f - dy)          * (vx0 * vy1);
    float wc = (1.0f - dx) * dy          * (vx1 * vy0);
    float wd = (1.0f - dx) * (1.0f - dy) * (vx1 * vy1);

    return wa * Ia + wb * Ib + wc * Ic + wd * Id;
}

__global__ __launch_bounds__(256) void st_bilinear_final(
    const float* __restrict__ img,   // [B,H,W,C]
    const float* __restrict__ def,   // [B,H,W,2]
    float* __restrict__ out)         // [B,H,W,C]
{
    int tid = blockIdx.x * 256 + threadIdx.x;   // [0, 8388608)
    int cq  = (tid & 3) << 2;                   // channel offset 0,4,8,12
    int pp  = tid >> 2;                         // pixel-pair index
    int xw  = pp & 511;
    int yh  = (pp >> 9) & 255;
    int b   = pp >> 17;
    int yr  = yh << 1;                          // even row
    int p0  = (b << 18) | (yr << 9) | xw;       // pixel index of row yr
    int p1  = p0 + W_;                          // pixel index of row yr+1

    const float* base = img + ((size_t)b << 22);

    v2f d0 = __builtin_nontemporal_load(
        reinterpret_cast<const v2f*>(def + ((size_t)p0 << 1)));
    v2f d1 = __builtin_nontemporal_load(
        reinterpret_cast<const v2f*>(def + ((size_t)p1 << 1)));

    v4f r0 = bilerp_quad(base, cq, xw, yr,     d0);
    v4f r1 = bilerp_quad(base, cq, xw, yr + 1, d1);

    __builtin_nontemporal_store(r0, reinterpret_cast<v4f*>(out + ((size_t)p0 << 4) + cq));
    __builtin_nontemporal_store(r1, reinterpret_cast<v4f*>(out + ((size_t)p1 << 4) + cq));
}

extern "C" void kernel_launch(void* const* d_in, const int* in_sizes, int n_in,
                              void* d_out, int out_size, void* d_ws, size_t ws_size,
                              hipStream_t stream) {
    const float* img = (const float*)d_in[0];   // moving_image [B,H,W,C]
    const float* def = (const float*)d_in[1];   // deformation  [B,H,W,2]
    float* out = (float*)d_out;

    const int total_threads = 16 * 512 * 512 * 4 / 2;  // 2 pixels per thread
    const int block = 256;
    const int grid = total_threads / block;            // 32768

    st_bilinear_final<<<grid, block, 0, stream>>>(img, def, out);
}